// Round 2
// baseline (224.255 us; speedup 1.0000x reference)
//
#include <hip/hip_runtime.h>
#include <cfloat>
#include <cmath>

// PillarEncoder fused kernel (MI355X / gfx950)
// out[b][c][y][x], shape (4, 64, 496, 432) fp32
#define XL 432
#define YL 496
#define NCH 64
#define HIMG 192
#define WIMG 640
#define PTS_M 32

#define WAVES 16            // 1024 threads -> 16 waves, 1 block/CU (LDS-capped), 4 waves/SIMD
#define TPB (WAVES * 64)
#define PPG 4               // pillars per group per wave
#define NBLOCKS 256
#define WPITCH 132          // padded row pitch (floats): breaks 512B-stride bank pattern, 16B-aligned rows

typedef const __attribute__((address_space(1))) void* gas_t;
typedef __attribute__((address_space(3))) void* las_t;

__device__ __forceinline__ void gload_lds16(const float* g, float* l) {
    // lane i: LDS[l + i*16] <- global[g_lane]   (wave-uniform LDS base, per-lane global addr)
    __builtin_amdgcn_global_load_lds((gas_t)g, (las_t)l, 16, 0, 0);
}

#define RED5(v) { v += __shfl_xor(v, 16); v += __shfl_xor(v, 8); v += __shfl_xor(v, 4); \
                  v += __shfl_xor(v, 2);  v += __shfl_xor(v, 1); }

template<bool ATOMIC>
__global__ __launch_bounds__(TPB, 4) void pillar_fused(
    const float* __restrict__ pillars,   // P*32*4
    const int*   __restrict__ coors,     // P*3 (b, ix, iy)
    const int*   __restrict__ npp,       // P
    const float* __restrict__ image,     // B*64*192*640
    const float* __restrict__ calibs,    // B*3*4
    const float* __restrict__ conv_w,    // 64*9
    const float* __restrict__ bng, const float* __restrict__ bnb,
    const float* __restrict__ bnm, const float* __restrict__ bnv,
    const float* __restrict__ w1, const float* __restrict__ b1,   // 128x128, 128
    const float* __restrict__ lng, const float* __restrict__ lnb, // 128
    const float* __restrict__ w2, const float* __restrict__ b2,   // 64x128, 64
    float* __restrict__ out, int P, int* __restrict__ cnt)
{
    __shared__ float w1p[128 * WPITCH];      // 66 KB, row-major padded: w1p[j*WPITCH+k] = w1[j][k]
    __shared__ float w2p[64 * WPITCH];       // 33 KB
    __shared__ float ws[WAVES][512];         // 2 KB/wave: points -> cat -> g (time-shared)

    const int tid  = threadIdx.x;
    const int lane = tid & 63;
    const int wv   = tid >> 6;

    // ---- stage weights (float4 both sides; padded rows keep banks spread) ----
    for (int i = tid; i < 128 * 32; i += TPB) {
        const int j = i >> 5, k4 = i & 31;
        ((float4*)(w1p + j * WPITCH))[k4] = ((const float4*)w1)[i];
    }
    for (int i = tid; i < 64 * 32; i += TPB) {
        const int j = i >> 5, k4 = i & 31;
        ((float4*)(w2p + j * WPITCH))[k4] = ((const float4*)w2)[i];
    }
    __syncthreads();

    // ---- per-channel folded conv+BN constants (lane = channel) ----
    float cw[9];
    #pragma unroll
    for (int i = 0; i < 9; ++i) cw[i] = conv_w[lane * 9 + i];
    const float s   = bng[lane] / sqrtf(bnv[lane] + 1e-3f);
    const float tch = bnb[lane] - bnm[lane] * s;      // BN(0): masked-row value
    const float As  = (cw[0] + cw[4] + cw[7]) * s;
    const float Bs  = (cw[1] + cw[5] + cw[8]) * s;
    const float Cs  = (cw[2] + cw[6]) * s;
    const float Ds  = cw[3] * s;
    const float w07 = (cw[0] + cw[7]) * s;
    const float w18 = (cw[1] + cw[8]) * s;
    const float w4s = cw[4] * s, w5s = cw[5] * s, w6s = cw[6] * s;

    const float b1a = b1[lane], b1b = b1[lane + 64];
    const float lga = lng[lane], lgb = lng[lane + 64];
    const float lba = lnb[lane], lbb = lnb[lane + 64];
    const float gb2 = b2[lane];

    float* wsw = ws[wv];
    const float4* wsf4 = (const float4*)wsw;
    const float4* w1rA = (const float4*)(w1p + lane * WPITCH);
    const float4* w1rB = (const float4*)(w1p + (lane + 64) * WPITCH);
    const float4* w2r  = (const float4*)(w2p + lane * WPITCH);

    const int ntasks = (P + PPG - 1) / PPG;
    int nextStatic = blockIdx.x * WAVES + wv;

    for (;;) {
        int grp;
        if (ATOMIC) {
            int g0 = 0;
            if (lane == 0) g0 = atomicAdd(cnt, 1);
            grp = __shfl(g0, 0);
        } else {
            grp = nextStatic;
            nextStatic += gridDim.x * WAVES;
        }
        if (grp >= ntasks) break;

        const int pbase = grp * PPG;
        const bool full = (pbase + PPG <= P);

        // ---------- stage 4 pillars' points (2 KB) into ws ----------
        asm volatile("s_waitcnt lgkmcnt(0)" ::: "memory");  // prior-iter LDS reads done before DMA overwrite
        if (full) {
            const float* src = pillars + (size_t)pbase * (PTS_M * 4);
            gload_lds16(src + lane * 4, wsw);               // pillars pbase, pbase+1
            gload_lds16(src + 256 + lane * 4, wsw + 256);   // pillars pbase+2, pbase+3
        } else {
            #pragma unroll
            for (int h = 0; h < 2; ++h) {
                const int idx = pbase * PTS_M + h * 64 + lane;   // float4 index
                float4 v = make_float4(0.f, 0.f, 0.f, 0.f);
                if (idx < P * PTS_M) v = ((const float4*)pillars)[idx];
                ((float4*)wsw)[h * 64 + lane] = v;
            }
        }

        // ---------- per-pillar scalars (uniform -> s_loads) ----------
        int bbv[PPG], ixv[PPG], iyv[PPG], nv[PPG];
        #pragma unroll
        for (int pp = 0; pp < PPG; ++pp) {
            const int p = pbase + pp;
            if (p < P) {
                bbv[pp] = coors[p * 3]; ixv[pp] = coors[p * 3 + 1];
                iyv[pp] = coors[p * 3 + 2]; nv[pp] = npp[p];
            } else {
                bbv[pp] = 0; ixv[pp] = 0; iyv[pp] = 0; nv[pp] = 1;
            }
        }

        asm volatile("s_waitcnt vmcnt(0) lgkmcnt(0)" ::: "memory");  // points in LDS

        // ---------- means: pairwise (pillars 0,1 in lanes 0-31/32-63; 2,3 likewise) ----------
        const float4 qa = wsf4[lane];        // pair A
        const float4 qb = wsf4[64 + lane];   // pair B
        float ax = qa.x, ay = qa.y, az = qa.z;
        float bx = qb.x, by = qb.y, bz = qb.z;
        RED5(ax) RED5(ay) RED5(az)
        RED5(bx) RED5(by) RED5(bz)
        const float axo = __shfl_xor(ax, 32), ayo = __shfl_xor(ay, 32), azo = __shfl_xor(az, 32);
        const float bxo = __shfl_xor(bx, 32), byo = __shfl_xor(by, 32), bzo = __shfl_xor(bz, 32);
        const bool lo = lane < 32;
        float mx[PPG], my[PPG], mz[PPG];
        {
            const float f0 = 1.f / (float)nv[0], f1 = 1.f / (float)nv[1];
            const float f2 = 1.f / (float)nv[2], f3 = 1.f / (float)nv[3];
            mx[0] = (lo ? ax : axo) * f0;  mx[1] = (lo ? axo : ax) * f1;
            my[0] = (lo ? ay : ayo) * f0;  my[1] = (lo ? ayo : ay) * f1;
            mz[0] = (lo ? az : azo) * f0;  mz[1] = (lo ? azo : az) * f1;
            mx[2] = (lo ? bx : bxo) * f2;  mx[3] = (lo ? bxo : bx) * f3;
            my[2] = (lo ? by : byo) * f2;  my[3] = (lo ? byo : by) * f3;
            mz[2] = (lo ? bz : bzo) * f2;  mz[3] = (lo ? bzo : bz) * f3;
        }

        // ---------- projection + image gather issue + folded bias ----------
        float img[PPG], Es[PPG];
        #pragma unroll
        for (int pp = 0; pp < PPG; ++pp) {
            const float* cb = calibs + bbv[pp] * 12;
            const float pr0 = cb[0]*mx[pp] + cb[1]*my[pp] + cb[2]*mz[pp] + cb[3];
            const float pr1 = cb[4]*mx[pp] + cb[5]*my[pp] + cb[6]*mz[pp] + cb[7];
            const float pr2 = cb[8]*mx[pp] + cb[9]*my[pp] + cb[10]*mz[pp] + cb[11];
            float uf = (pr0 / pr2) * 0.5f;
            float vf = (pr1 / pr2) * 0.5f;
            uf = fminf(fmaxf(uf, 0.f), (float)(WIMG - 1));
            vf = fminf(fmaxf(vf, 0.f), (float)(HIMG - 1));
            const int u = (int)uf, v = (int)vf;
            img[pp] = image[(((bbv[pp] * NCH) + lane) * HIMG + v) * WIMG + u];  // issued early, used late

            const float cxp = (float)ixv[pp] * 0.16f + 0.08f;
            const float cyp = (float)iyv[pp] * 0.16f + (-39.6f);
            Es[pp] = tch - (cxp * w07 + cyp * w18 + mx[pp] * w4s + my[pp] * w5s + mz[pp] * w6s);
        }

        // ---------- pooled max: unrolled 32-pt masked loop, LDS broadcast reads ----------
        float pooled[PPG];
        #pragma unroll
        for (int pp = 0; pp < PPG; ++pp) {
            const int n = nv[pp];
            float p0 = (n < PTS_M) ? tch : -FLT_MAX;
            float p1 = -FLT_MAX, p2 = -FLT_MAX, p3 = -FLT_MAX;
            #pragma unroll
            for (int m = 0; m < PTS_M; m += 4) {
                const float4 q0 = wsf4[pp * 32 + m];
                const float4 q1 = wsf4[pp * 32 + m + 1];
                const float4 q2 = wsf4[pp * 32 + m + 2];
                const float4 q3 = wsf4[pp * 32 + m + 3];
                const float h0 = Es[pp] + q0.x*As + q0.y*Bs + q0.z*Cs + q0.w*Ds;
                const float h1 = Es[pp] + q1.x*As + q1.y*Bs + q1.z*Cs + q1.w*Ds;
                const float h2 = Es[pp] + q2.x*As + q2.y*Bs + q2.z*Cs + q2.w*Ds;
                const float h3 = Es[pp] + q3.x*As + q3.y*Bs + q3.z*Cs + q3.w*Ds;
                p0 = fmaxf(p0, (m     < n) ? h0 : -FLT_MAX);
                p1 = fmaxf(p1, (m + 1 < n) ? h1 : -FLT_MAX);
                p2 = fmaxf(p2, (m + 2 < n) ? h2 : -FLT_MAX);
                p3 = fmaxf(p3, (m + 3 < n) ? h3 : -FLT_MAX);
            }
            pooled[pp] = fmaxf(fmaxf(fmaxf(p0, p1), fmaxf(p2, p3)), 0.f);  // relu commutes with max
        }

        // ---------- cat -> ws (overwrites points; all point reads done) ----------
        #pragma unroll
        for (int pp = 0; pp < PPG; ++pp) {
            wsw[pp * 128 + lane]      = pooled[pp];
            wsw[pp * 128 + 64 + lane] = img[pp];
        }
        asm volatile("s_waitcnt lgkmcnt(0)" ::: "memory");

        // ---------- GEMM1: b128 weight rows + b128 cat broadcasts ----------
        float accA[PPG], accB[PPG];
        #pragma unroll
        for (int pp = 0; pp < PPG; ++pp) { accA[pp] = b1a; accB[pp] = b1b; }
        #pragma unroll 4
        for (int k4 = 0; k4 < 32; ++k4) {
            const float4 wa = w1rA[k4];
            const float4 wb = w1rB[k4];
            #pragma unroll
            for (int pp = 0; pp < PPG; ++pp) {
                const float4 cv = wsf4[pp * 32 + k4];
                accA[pp] += cv.x*wa.x + cv.y*wa.y + cv.z*wa.z + cv.w*wa.w;
                accB[pp] += cv.x*wb.x + cv.y*wb.y + cv.z*wb.z + cv.w*wb.w;
            }
        }

        // ---------- LayerNorm(128) + relu -> ws ----------
        float sum[PPG], sq[PPG];
        #pragma unroll
        for (int pp = 0; pp < PPG; ++pp) {
            sum[pp] = accA[pp] + accB[pp];
            sq[pp]  = accA[pp]*accA[pp] + accB[pp]*accB[pp];
        }
        #pragma unroll
        for (int d = 32; d; d >>= 1) {
            #pragma unroll
            for (int pp = 0; pp < PPG; ++pp) {
                sum[pp] += __shfl_xor(sum[pp], d);
                sq[pp]  += __shfl_xor(sq[pp], d);
            }
        }
        #pragma unroll
        for (int pp = 0; pp < PPG; ++pp) {
            const float mu  = sum[pp] * (1.f / 128.f);
            const float var = sq[pp] * (1.f / 128.f) - mu * mu;
            const float inv = 1.f / sqrtf(var + 1e-5f);
            const float g0 = (accA[pp] - mu) * inv * lga + lba;
            const float g1 = (accB[pp] - mu) * inv * lgb + lbb;
            wsw[pp * 128 + lane]      = fmaxf(g0, 0.f);
            wsw[pp * 128 + 64 + lane] = fmaxf(g1, 0.f);
        }
        asm volatile("s_waitcnt lgkmcnt(0)" ::: "memory");

        // ---------- GEMM2 + sigmoid gate + blend + scatter ----------
        float ac2[PPG];
        #pragma unroll
        for (int pp = 0; pp < PPG; ++pp) ac2[pp] = gb2;
        #pragma unroll 4
        for (int k4 = 0; k4 < 32; ++k4) {
            const float4 w = w2r[k4];
            #pragma unroll
            for (int pp = 0; pp < PPG; ++pp) {
                const float4 gv = wsf4[pp * 32 + k4];
                ac2[pp] += gv.x*w.x + gv.y*w.y + gv.z*w.z + gv.w*w.w;
            }
        }
        #pragma unroll
        for (int pp = 0; pp < PPG; ++pp) {
            const int p = pbase + pp;
            if (p >= P) continue;
            const float gate = 1.f / (1.f + expf(-ac2[pp]));
            const float gf = pooled[pp] * gate + img[pp] * (1.f - gate);
            out[(((bbv[pp] * NCH) + lane) * YL + iyv[pp]) * XL + ixv[pp]] = gf;
        }
    }
}

extern "C" void kernel_launch(void* const* d_in, const int* in_sizes, int n_in,
                              void* d_out, int out_size, void* d_ws, size_t ws_size,
                              hipStream_t stream)
{
    const float* pillars = (const float*)d_in[0];
    const int*   coors   = (const int*)d_in[1];
    const int*   npp     = (const int*)d_in[2];
    const float* image   = (const float*)d_in[3];
    const float* calibs  = (const float*)d_in[4];
    const float* conv_w  = (const float*)d_in[6];
    const float* bng     = (const float*)d_in[7];
    const float* bnb     = (const float*)d_in[8];
    const float* bnm     = (const float*)d_in[9];
    const float* bnv     = (const float*)d_in[10];
    const float* w1      = (const float*)d_in[11];
    const float* b1      = (const float*)d_in[12];
    const float* lng     = (const float*)d_in[13];
    const float* lnb     = (const float*)d_in[14];
    const float* w2      = (const float*)d_in[15];
    const float* b2      = (const float*)d_in[16];
    float* out = (float*)d_out;
    const int P = in_sizes[0] / (PTS_M * 4);

    hipMemsetAsync(d_out, 0, (size_t)out_size * sizeof(float), stream);
    if (ws_size >= 4) {
        hipMemsetAsync(d_ws, 0, 4, stream);   // work-stealing counter (in-graph reset)
        pillar_fused<true><<<dim3(NBLOCKS), dim3(TPB), 0, stream>>>(
            pillars, coors, npp, image, calibs, conv_w, bng, bnb, bnm, bnv,
            w1, b1, lng, lnb, w2, b2, out, P, (int*)d_ws);
    } else {
        pillar_fused<false><<<dim3(NBLOCKS), dim3(TPB), 0, stream>>>(
            pillars, coors, npp, image, calibs, conv_w, bng, bnb, bnm, bnv,
            w1, b1, lng, lnb, w2, b2, out, P, nullptr);
    }
}